// Round 1
// baseline (4514.962 us; speedup 1.0000x reference)
//
#include <hip/hip_runtime.h>
#include <math.h>

#define NN 16384
#define FF 128
#define NRB 32
#define EE 262144
#define TE 32

__device__ __forceinline__ float silu_f(float x) { return x / (1.0f + expf(-x)); }
__device__ __forceinline__ int degmap(int j) { return (j == 0) ? 0 : (j < 4) ? 1 : (j < 9) ? 2 : 3; }

// ---------------------------------------------------------------------------
// Kernel 1: per-node projections q/k/v_inv (8 heads of 16x16), q/k_ev (4 of 32x32)
// ---------------------------------------------------------------------------
__global__ __launch_bounds__(128) void node_proj(
    const float* __restrict__ inv,
    const float* __restrict__ Wq_inv, const float* __restrict__ Wk_inv,
    const float* __restrict__ Wv_inv,
    const float* __restrict__ Wq_ev, const float* __restrict__ Wk_ev,
    float* __restrict__ q_inv, float* __restrict__ k_inv, float* __restrict__ v_inv,
    float* __restrict__ q_ev, float* __restrict__ k_ev)
{
    const int n = blockIdx.x;
    const int t = threadIdx.x;
    __shared__ float x[128];
    x[t] = inv[n * 128 + t];
    __syncthreads();

    // inv heads: h = t>>4, out elem e = t&15
    {
        const int h = t >> 4, e = t & 15;
        const float* wq = Wq_inv + h * 256;
        const float* wk = Wk_inv + h * 256;
        const float* wv = Wv_inv + h * 256;
        float aq = 0.f, ak = 0.f, av = 0.f;
        #pragma unroll
        for (int d = 0; d < 16; ++d) {
            const float xv = x[h * 16 + d];
            aq += xv * wq[d * 16 + e];
            ak += xv * wk[d * 16 + e];
            av += xv * wv[d * 16 + e];
        }
        q_inv[n * 128 + t] = aq;
        k_inv[n * 128 + t] = ak;
        v_inv[n * 128 + t] = av;
    }
    // ev degrees: l = t>>5, out elem e = t&31
    {
        const int l = t >> 5, e = t & 31;
        const float* wq = Wq_ev + l * 1024;
        const float* wk = Wk_ev + l * 1024;
        float aq = 0.f, ak = 0.f;
        #pragma unroll
        for (int d = 0; d < 32; ++d) {
            const float xv = x[l * 32 + d];
            aq += xv * wq[d * 32 + e];
            ak += xv * wk[d * 32 + e];
        }
        q_ev[n * 128 + t] = aq;
        k_ev[n * 128 + t] = ak;
    }
}

// ---------------------------------------------------------------------------
// Kernel 2: fused per-edge filter nets + attention + scatter
//   256 threads, TE=32 edges/block. Each thread owns a 4-edge x 4-col tile.
// ---------------------------------------------------------------------------
__global__ __launch_bounds__(256) void edge_kernel(
    const float* __restrict__ ev_feat,
    const float* __restrict__ rbf,
    const float* __restrict__ sh,
    const float* __restrict__ cutoffs,
    const int* __restrict__ senders,
    const int* __restrict__ receivers,
    const float* __restrict__ fi_w1r, const float* __restrict__ fi_b1r,
    const float* __restrict__ fi_w2r, const float* __restrict__ fi_b2r,
    const float* __restrict__ fi_w1e, const float* __restrict__ fi_b1e,
    const float* __restrict__ fi_w2e, const float* __restrict__ fi_b2e,
    const float* __restrict__ fe_w1r, const float* __restrict__ fe_b1r,
    const float* __restrict__ fe_w2r, const float* __restrict__ fe_b2r,
    const float* __restrict__ fe_w1e, const float* __restrict__ fe_b1e,
    const float* __restrict__ fe_w2e, const float* __restrict__ fe_b2e,
    const float* __restrict__ q_inv, const float* __restrict__ k_inv,
    const float* __restrict__ v_inv,
    const float* __restrict__ q_ev, const float* __restrict__ k_ev,
    float* __restrict__ att_inv, float* __restrict__ att_ev)
{
    __shared__ float h1[TE][128];      // stage-1 hidden
    __shared__ float wbuf[32][128];    // staged weight chunk (reused)
    __shared__ float rbf_t[TE][NRB];
    __shared__ float he1[TE][32];
    __shared__ float evinv_t[TE][4];
    __shared__ float w1e_s[128];
    __shared__ float alpha_e[TE][4];
    __shared__ int sidx[TE];
    __shared__ int ridx[TE];
    __shared__ float cut[TE];

    const int tid = threadIdx.x;
    const int e0 = blockIdx.x * TE;

    if (tid < TE) {
        sidx[tid] = senders[e0 + tid];
        ridx[tid] = receivers[e0 + tid];
        cut[tid] = cutoffs[e0 + tid];
    }
    for (int i = tid; i < TE * NRB; i += 256)
        rbf_t[i >> 5][i & 31] = rbf[e0 * NRB + i];
    __syncthreads();

    // ev_diff l0-contraction (one thread per edge)
    if (tid < TE) {
        const float* es = ev_feat + sidx[tid] * 16;
        const float* er = ev_feat + ridx[tid] * 16;
        float d = es[0] - er[0];
        evinv_t[tid][0] = d * d;
        float a = 0.f;
        for (int j = 1; j < 4; ++j) { d = es[j] - er[j]; a += d * d; }
        evinv_t[tid][1] = a;
        a = 0.f;
        for (int j = 4; j < 9; ++j) { d = es[j] - er[j]; a += d * d; }
        evinv_t[tid][2] = a;
        a = 0.f;
        for (int j = 9; j < 16; ++j) { d = es[j] - er[j]; a += d * d; }
        evinv_t[tid][3] = a;
    }

    const int eg = tid >> 5;   // 0..7 : edge group (4 edges each)
    const int cg = tid & 31;   // 0..31: col group (4 cols each)
    const int cb = cg * 4;

    for (int p = 0; p < 2; ++p) {
        const float* w1r = p ? fe_w1r : fi_w1r;
        const float* b1r = p ? fe_b1r : fi_b1r;
        const float* w2r = p ? fe_w2r : fi_w2r;
        const float* b2r = p ? fe_b2r : fi_b2r;
        const float* w1e = p ? fe_w1e : fi_w1e;
        const float* b1e = p ? fe_b1e : fi_b1e;
        const float* w2e = p ? fe_w2e : fi_w2e;
        const float* b2e = p ? fe_b2e : fi_b2e;

        // ---- stage w1r (32x128) ----
        for (int i = tid; i < 32 * 128; i += 256) wbuf[i >> 7][i & 127] = w1r[i];
        if (tid < 128) w1e_s[tid] = w1e[tid];
        __syncthreads();

        // ---- stage 1: h1 = silu(rbf @ w1r + b1r) ----
        {
            float hacc[4][4];
            float bj0 = b1r[cb], bj1 = b1r[cb + 1], bj2 = b1r[cb + 2], bj3 = b1r[cb + 3];
            #pragma unroll
            for (int i = 0; i < 4; ++i) {
                hacc[i][0] = bj0; hacc[i][1] = bj1; hacc[i][2] = bj2; hacc[i][3] = bj3;
            }
            for (int k = 0; k < 32; ++k) {
                const float4 w4 = *reinterpret_cast<const float4*>(&wbuf[k][cb]);
                #pragma unroll
                for (int i = 0; i < 4; ++i) {
                    const float xv = rbf_t[eg * 4 + i][k];
                    hacc[i][0] += xv * w4.x; hacc[i][1] += xv * w4.y;
                    hacc[i][2] += xv * w4.z; hacc[i][3] += xv * w4.w;
                }
            }
            #pragma unroll
            for (int i = 0; i < 4; ++i) {
                float4 hv;
                hv.x = silu_f(hacc[i][0]); hv.y = silu_f(hacc[i][1]);
                hv.z = silu_f(hacc[i][2]); hv.w = silu_f(hacc[i][3]);
                *reinterpret_cast<float4*>(&h1[eg * 4 + i][cb]) = hv;
            }
        }
        // ---- he1 = silu(evinv @ w1e + b1e) ----
        for (int i = tid; i < TE * 32; i += 256) {
            const int e = i >> 5, j2 = i & 31;
            float a = b1e[j2];
            #pragma unroll
            for (int k = 0; k < 4; ++k) a += evinv_t[e][k] * w1e_s[k * 32 + j2];
            he1[e][j2] = silu_f(a);
        }
        __syncthreads();

        // ---- stage 2: fw = h1 @ w2r + he1 @ w2e + b2r + b2e (kept in registers) ----
        float acc[4][4];
        {
            const float b0 = b2r[cb] + b2e[cb];
            const float b1 = b2r[cb + 1] + b2e[cb + 1];
            const float b2 = b2r[cb + 2] + b2e[cb + 2];
            const float b3 = b2r[cb + 3] + b2e[cb + 3];
            #pragma unroll
            for (int i = 0; i < 4; ++i) {
                acc[i][0] = b0; acc[i][1] = b1; acc[i][2] = b2; acc[i][3] = b3;
            }
        }
        for (int cc = 0; cc < 4; ++cc) {
            for (int i = tid; i < 32 * 128; i += 256) wbuf[i >> 7][i & 127] = w2r[cc * 4096 + i];
            __syncthreads();
            for (int kk = 0; kk < 32; ++kk) {
                const float4 w4 = *reinterpret_cast<const float4*>(&wbuf[kk][cb]);
                #pragma unroll
                for (int i = 0; i < 4; ++i) {
                    const float xv = h1[eg * 4 + i][cc * 32 + kk];
                    acc[i][0] += xv * w4.x; acc[i][1] += xv * w4.y;
                    acc[i][2] += xv * w4.z; acc[i][3] += xv * w4.w;
                }
            }
            __syncthreads();
        }
        // w2e chunk (he1 operand)
        for (int i = tid; i < 32 * 128; i += 256) wbuf[i >> 7][i & 127] = w2e[i];
        __syncthreads();
        for (int kk = 0; kk < 32; ++kk) {
            const float4 w4 = *reinterpret_cast<const float4*>(&wbuf[kk][cb]);
            #pragma unroll
            for (int i = 0; i < 4; ++i) {
                const float xv = he1[eg * 4 + i][kk];
                acc[i][0] += xv * w4.x; acc[i][1] += xv * w4.y;
                acc[i][2] += xv * w4.z; acc[i][3] += xv * w4.w;
            }
        }
        __syncthreads();

        // ---- attention + scatter ----
        if (p == 0) {
            // inv attention: head h = c/16 -> lanes cg in [4h, 4h+3]
            #pragma unroll
            for (int i = 0; i < 4; ++i) {
                const int e = eg * 4 + i;
                const int s = sidx[e], r = ridx[e];
                const float4 q4 = *reinterpret_cast<const float4*>(q_inv + r * 128 + cb);
                const float4 k4 = *reinterpret_cast<const float4*>(k_inv + s * 128 + cb);
                const float4 v4 = *reinterpret_cast<const float4*>(v_inv + s * 128 + cb);
                float part = q4.x * k4.x * acc[i][0] + q4.y * k4.y * acc[i][1]
                           + q4.z * k4.z * acc[i][2] + q4.w * k4.w * acc[i][3];
                part += __shfl_xor(part, 1);
                part += __shfl_xor(part, 2);
                const float am = part * 0.25f * cut[e];  // /sqrt(16) * cutoff
                float* dst = att_inv + r * 128 + cb;
                atomicAdd(dst + 0, am * v4.x);
                atomicAdd(dst + 1, am * v4.y);
                atomicAdd(dst + 2, am * v4.z);
                atomicAdd(dst + 3, am * v4.w);
            }
        } else {
            // ev attention: degree l = c/32 -> lanes cg in [8l, 8l+7]
            #pragma unroll
            for (int i = 0; i < 4; ++i) {
                const int e = eg * 4 + i;
                const int s = sidx[e], r = ridx[e];
                const float4 q4 = *reinterpret_cast<const float4*>(q_ev + r * 128 + cb);
                const float4 k4 = *reinterpret_cast<const float4*>(k_ev + s * 128 + cb);
                float part = q4.x * k4.x * acc[i][0] + q4.y * k4.y * acc[i][1]
                           + q4.z * k4.z * acc[i][2] + q4.w * k4.w * acc[i][3];
                part += __shfl_xor(part, 1);
                part += __shfl_xor(part, 2);
                part += __shfl_xor(part, 4);
                if ((cg & 7) == 0)
                    alpha_e[e][cg >> 3] = part * 0.17677669529663687f;  // 1/sqrt(32)
            }
            __syncthreads();
            for (int i2 = tid; i2 < TE * 16; i2 += 256) {
                const int e = i2 >> 4, j = i2 & 15;
                const int r = ridx[e];
                const float contrib = cut[e] * alpha_e[e][degmap(j)] * sh[(e0 + e) * 16 + j];
                atomicAdd(&att_ev[r * 16 + j], contrib);
            }
        }
        __syncthreads();
    }
}

// ---------------------------------------------------------------------------
// Kernel 3: final node update (132x132 MLP) + outputs
// ---------------------------------------------------------------------------
__global__ __launch_bounds__(128) void final_kernel(
    const float* __restrict__ inv, const float* __restrict__ ev,
    const float* __restrict__ att_inv, const float* __restrict__ att_ev,
    const float* __restrict__ int_w, const float* __restrict__ int_b,
    float* __restrict__ out0, float* __restrict__ out1)
{
    const int n = blockIdx.x;
    const int t = threadIdx.x;
    __shared__ float xin[132];
    __shared__ float ev1s[16];
    __shared__ float tcol[4];

    const float iv = inv[n * 128 + t] + att_inv[n * 128 + t];
    xin[t] = iv;
    if (t < 16) ev1s[t] = ev[n * 16 + t] + att_ev[n * 16 + t];
    __syncthreads();
    if (t < 4) {
        const int st = (t == 0) ? 0 : (t == 1) ? 1 : (t == 2) ? 4 : 9;
        const int en = (t == 0) ? 1 : (t == 1) ? 4 : (t == 2) ? 9 : 16;
        float a = 0.f;
        for (int j = st; j < en; ++j) a += ev1s[j] * ev1s[j];
        xin[128 + t] = a;
    }
    __syncthreads();

    float acc = int_b[t];
    for (int k = 0; k < 132; ++k) acc += xin[k] * int_w[k * 132 + t];
    out0[n * 128 + t] = iv + acc;

    if (t < 4) {
        float a2 = int_b[128 + t];
        for (int k = 0; k < 132; ++k) a2 += xin[k] * int_w[k * 132 + 128 + t];
        tcol[t] = a2;
    }
    __syncthreads();
    if (t < 16) out1[n * 16 + t] = ev1s[t] * (1.0f + tcol[degmap(t)]);
}

// ---------------------------------------------------------------------------
extern "C" void kernel_launch(void* const* d_in, const int* in_sizes, int n_in,
                              void* d_out, int out_size, void* d_ws, size_t ws_size,
                              hipStream_t stream) {
    const float* inv_features = (const float*)d_in[0];
    const float* ev_features  = (const float*)d_in[1];
    const float* rbf          = (const float*)d_in[2];
    const float* sh_vectors   = (const float*)d_in[3];
    const float* cutoffs      = (const float*)d_in[4];
    const int*   senders      = (const int*)d_in[5];
    const int*   receivers    = (const int*)d_in[6];
    const float* fi_rbf_w1 = (const float*)d_in[7];
    const float* fi_rbf_b1 = (const float*)d_in[8];
    const float* fi_rbf_w2 = (const float*)d_in[9];
    const float* fi_rbf_b2 = (const float*)d_in[10];
    const float* fi_ev_w1  = (const float*)d_in[11];
    const float* fi_ev_b1  = (const float*)d_in[12];
    const float* fi_ev_w2  = (const float*)d_in[13];
    const float* fi_ev_b2  = (const float*)d_in[14];
    const float* fe_rbf_w1 = (const float*)d_in[15];
    const float* fe_rbf_b1 = (const float*)d_in[16];
    const float* fe_rbf_w2 = (const float*)d_in[17];
    const float* fe_rbf_b2 = (const float*)d_in[18];
    const float* fe_ev_w1  = (const float*)d_in[19];
    const float* fe_ev_b1  = (const float*)d_in[20];
    const float* fe_ev_w2  = (const float*)d_in[21];
    const float* fe_ev_b2  = (const float*)d_in[22];
    const float* Wq_inv = (const float*)d_in[23];
    const float* Wk_inv = (const float*)d_in[24];
    const float* Wv_inv = (const float*)d_in[25];
    const float* Wq_ev  = (const float*)d_in[26];
    const float* Wk_ev  = (const float*)d_in[27];
    const float* int_w  = (const float*)d_in[28];
    const float* int_b  = (const float*)d_in[29];

    float* ws = (float*)d_ws;
    float* q_inv = ws;
    float* k_inv = ws + (size_t)NN * 128;
    float* v_inv = ws + (size_t)NN * 256;
    float* q_ev  = ws + (size_t)NN * 384;
    float* k_ev  = ws + (size_t)NN * 512;
    float* att_inv = ws + (size_t)NN * 640;   // N*128
    float* att_ev  = ws + (size_t)NN * 768;   // N*16 (contiguous after att_inv)

    // zero the attention accumulators (N*144 floats, contiguous)
    hipMemsetAsync(att_inv, 0, (size_t)NN * 144 * sizeof(float), stream);

    node_proj<<<NN, 128, 0, stream>>>(inv_features, Wq_inv, Wk_inv, Wv_inv,
                                      Wq_ev, Wk_ev, q_inv, k_inv, v_inv, q_ev, k_ev);

    edge_kernel<<<EE / TE, 256, 0, stream>>>(
        ev_features, rbf, sh_vectors, cutoffs, senders, receivers,
        fi_rbf_w1, fi_rbf_b1, fi_rbf_w2, fi_rbf_b2,
        fi_ev_w1, fi_ev_b1, fi_ev_w2, fi_ev_b2,
        fe_rbf_w1, fe_rbf_b1, fe_rbf_w2, fe_rbf_b2,
        fe_ev_w1, fe_ev_b1, fe_ev_w2, fe_ev_b2,
        q_inv, k_inv, v_inv, q_ev, k_ev, att_inv, att_ev);

    final_kernel<<<NN, 128, 0, stream>>>(inv_features, ev_features, att_inv, att_ev,
                                         int_w, int_b,
                                         (float*)d_out, (float*)d_out + (size_t)NN * 128);
}